// Round 1
// baseline (150.156 us; speedup 1.0000x reference)
//
#include <hip/hip_runtime.h>
#include <hip/hip_bf16.h>

#define D_IN   246
#define NW     10     // wires / hidden units
#define NG     4      // gates
#define NOUT   40     // NG*NW
#define FANIN  256    // D_IN + NW
#define BATCH  256
#define TSTEPS 64

// Kernel 1: zx[t][b][g*10+o] = sum_i x[t,b,i] * W[g,o,i]  + bias[g,o] + theta[g,o]
// grid (64 t, 4 bq), block 256 (4 waves; wave w == gate g)
__global__ __launch_bounds__(256) void k_zx(
    const float* __restrict__ x,      // (64,256,246)
    const float* __restrict__ W,      // (4,10,256)
    const float* __restrict__ bias,   // (4,10)
    const float* __restrict__ theta,  // (4,10)
    float* __restrict__ zx)           // (64,256,40)
{
    const int t    = blockIdx.x;
    const int bq   = blockIdx.y;
    const int wave = threadIdx.x >> 6;   // = gate g
    const int lane = threadIdx.x & 63;
    const int b    = bq * 64 + lane;

    __shared__ float Wl[NG][D_IN][NW];   // 39.36 KB

    // stage this wave's gate columns of W into LDS (coalesced over i)
    for (int e = lane; e < D_IN * NW; e += 64) {
        int o = e / D_IN;
        int i = e - o * D_IN;
        Wl[wave][i][o] = W[(wave * NW + o) * FANIN + i];
    }
    __syncthreads();

    float acc[NW];
#pragma unroll
    for (int o = 0; o < NW; ++o)
        acc[o] = bias[wave * NW + o] + theta[wave * NW + o];

    const float* xr = x + (size_t)(t * BATCH + b) * D_IN;  // row base 8B-aligned (984B rows)
#pragma unroll 2
    for (int i = 0; i < D_IN; i += 2) {
        float2 xv = *reinterpret_cast<const float2*>(xr + i);
#pragma unroll
        for (int o = 0; o < NW; ++o) {
            acc[o] += xv.x * Wl[wave][i][o];
            acc[o] += xv.y * Wl[wave][i + 1][o];
        }
    }

    float* zo = zx + (size_t)(t * BATCH + b) * NOUT + wave * NW;
#pragma unroll
    for (int o = 0; o < NW; ++o) zo[o] = acc[o];
}

// Kernel 2: sequential LSTM scan, one wave per batch element.
// lane = g*16 + o (o<10 active). Gate value = prefix product of cosines.
__global__ __launch_bounds__(64) void k_scan(
    const float* __restrict__ zx,   // (64,256,40)
    const float* __restrict__ W,    // (4,10,256): hx weights at cols 246..255
    float* __restrict__ out,        // (64,256,10)
    float* __restrict__ hxout,      // (256,10)
    float* __restrict__ cxout)      // (256,10)
{
    const int b    = blockIdx.x;
    const int lane = threadIdx.x;
    const int g    = lane >> 4;
    const int o    = lane & 15;
    const bool act = (o < NW);
    const int oc   = act ? o : 0;

    // per-lane recurrent weights Wh[g][o][j]
    float wh[NW];
#pragma unroll
    for (int j = 0; j < NW; ++j)
        wh[j] = W[(g * NW + oc) * FANIN + D_IN + j];

    float hxr[NW];
#pragma unroll
    for (int j = 0; j < NW; ++j) hxr[j] = 0.f;
    float cx = 0.f;
    float hv = 0.f;

    for (int t = 0; t < TSTEPS; ++t) {
        // z = zx + hx . Wh
        float z = act ? zx[(size_t)(t * BATCH + b) * NOUT + g * NW + oc] : 0.f;
#pragma unroll
        for (int j = 0; j < NW; ++j) z += hxr[j] * wh[j];

        float c = act ? __cosf(z) : 1.f;

        // inclusive prefix product over the 16-lane group (lanes >=10 carry 1.0)
        float p = c;
#pragma unroll
        for (int s = 1; s < 16; s <<= 1) {
            float up = __shfl_up(p, s, 16);
            if ((lane & 15) >= s) p *= up;
        }

        // gate nonlinearity: sigmoid for f,i,o ; tanh for g (=2*sigmoid(2x)-1)
        float a  = (g == 2) ? 2.f * p : p;
        float sg = 1.f / (1.f + __expf(-a));
        float val = (g == 2) ? (2.f * sg - 1.f) : sg;

        // gather the four gate values onto the g==0 lanes
        float fi = val;
        float ii = __shfl(val, 16 + o);
        float gg = __shfl(val, 32 + o);
        float oo = __shfl(val, 48 + o);

        cx = fi * cx + ii * gg;
        float th = tanhf(cx);
        hv = oo * th;

        if (g == 0 && act) out[(size_t)(t * BATCH + b) * NW + o] = hv;

        // broadcast new hx[0..9] (held by lanes 0..9) to every lane
#pragma unroll
        for (int j = 0; j < NW; ++j) hxr[j] = __shfl(hv, j);
    }

    if (g == 0 && act) {
        hxout[b * NW + o] = hv;
        cxout[b * NW + o] = cx;
    }
}

extern "C" void kernel_launch(void* const* d_in, const int* in_sizes, int n_in,
                              void* d_out, int out_size, void* d_ws, size_t ws_size,
                              hipStream_t stream) {
    const float* x     = (const float*)d_in[0];  // (64,256,246)
    const float* W     = (const float*)d_in[1];  // (4,10,256)
    const float* bias  = (const float*)d_in[2];  // (4,10)
    const float* theta = (const float*)d_in[3];  // (4,10)

    float* out   = (float*)d_out;                        // (64,256,10)
    float* hxout = out + (size_t)TSTEPS * BATCH * NW;    // (256,10)
    float* cxout = hxout + (size_t)BATCH * NW;           // (256,10)

    float* zx = (float*)d_ws;   // (64,256,40) = 2.62 MB scratch

    dim3 g1(TSTEPS, 4);
    k_zx<<<g1, 256, 0, stream>>>(x, W, bias, theta, zx);
    k_scan<<<BATCH, 64, 0, stream>>>(zx, W, out, hxout, cxout);
}

// Round 3
// 126.231 us; speedup vs baseline: 1.1895x; 1.1895x over previous
//
#include <hip/hip_runtime.h>
#include <hip/hip_bf16.h>

#define D_IN   246
#define NW     10
#define NG     4
#define NOUT   40
#define FANIN  256
#define BATCH  256
#define TSTEPS 64
#define XP     248          // padded LDS row stride (floats), 992 B = 16B-aligned rows
#define WP_ELEMS (NG * D_IN * 16)   // 15744 floats, padded-o W

// ---------------- Kernel 0: transpose W -> Wp[g][i][16] (o padded to 16) ---------
__global__ __launch_bounds__(256) void k_wt(const float* __restrict__ W,
                                            float* __restrict__ Wp) {
    int e = blockIdx.x * 256 + threadIdx.x;
    if (e >= WP_ELEMS) return;
    int o = e & 15;
    int i = (e >> 4) % D_IN;
    int g = e / (16 * D_IN);
    float v = (o < NW) ? W[(g * NW + o) * FANIN + i] : 0.f;
    Wp[e] = v;
}

// ---------------- Kernel 1: zxT[b][t][g*10+o] = x.W + bias + theta ---------------
// grid (64 t, 4 bq), block 256 = 4 waves; wave == gate g; lane == local b.
__global__ __launch_bounds__(256) void k_zx(
    const float* __restrict__ x,      // (64,256,246)
    const float* __restrict__ Wp,     // (4,246,16) transposed/padded
    const float* __restrict__ bias,   // (4,10)
    const float* __restrict__ theta,  // (4,10)
    float* __restrict__ zxT)          // (256,64,40)  b-major!
{
    const int t   = blockIdx.x;
    const int bq  = blockIdx.y;
    const int tid = threadIdx.x;
    const int lane = tid & 63;
    // wave id, forced wave-uniform so W/bias reads scalarize to s_load
    const int g = __builtin_amdgcn_readfirstlane(tid >> 6);

    __shared__ float xl[64 * XP];     // 63.5 KB

    // coalesced stage: 64 rows x 123 float2
    const float* xsrc = x + ((size_t)t * BATCH + bq * 64) * D_IN;
    for (int k = tid; k < 64 * 123; k += 256) {
        int row = k / 123;
        int j   = k - row * 123;
        float2 v = *reinterpret_cast<const float2*>(xsrc + row * D_IN + 2 * j);
        *reinterpret_cast<float2*>(xl + row * XP + 2 * j) = v;
    }
    __syncthreads();

    float acc[NW];
#pragma unroll
    for (int o = 0; o < NW; ++o)
        acc[o] = bias[g * NW + o] + theta[g * NW + o];   // uniform -> s_load

    const float* wg = Wp + g * D_IN * 16;                // uniform base
    const float* xr = xl + lane * XP;

#pragma unroll 1
    for (int i = 0; i < 244; i += 4) {
        float4 xv = *reinterpret_cast<const float4*>(xr + i);
        const float xs[4] = {xv.x, xv.y, xv.z, xv.w};
#pragma unroll
        for (int k2 = 0; k2 < 4; ++k2) {
#pragma unroll
            for (int o = 0; o < NW; ++o)
                acc[o] += xs[k2] * wg[(i + k2) * 16 + o];
        }
    }
    // tail i = 244, 245
    {
        float2 xv = *reinterpret_cast<const float2*>(xr + 244);
#pragma unroll
        for (int o = 0; o < NW; ++o) {
            acc[o] += xv.x * wg[244 * 16 + o];
            acc[o] += xv.y * wg[245 * 16 + o];
        }
    }

    const int b = bq * 64 + lane;
    float* zo = zxT + ((size_t)b * TSTEPS + t) * NOUT + g * NW;
#pragma unroll
    for (int o = 0; o < NW; ++o) zo[o] = acc[o];
}

// ---------------- Kernel 2: sequential LSTM scan, one wave per batch element ----
template <int CTRL>
__device__ __forceinline__ float dpp_shr_mul(float p) {
    // p *= (lane has a source s below in the row ? p_from(lane-s) : 1.0)
    int up = __builtin_amdgcn_update_dpp(__float_as_int(1.0f), __float_as_int(p),
                                         CTRL, 0xF, 0xF, false);
    return p * __int_as_float(up);
}

__global__ __launch_bounds__(64) void k_scan(
    const float* __restrict__ zxT,  // (256,64,40)
    const float* __restrict__ W,    // (4,10,256): recurrent cols 246..255
    float* __restrict__ out,        // (64,256,10)
    float* __restrict__ hxout,      // (256,10)
    float* __restrict__ cxout)      // (256,10)
{
    const int b    = blockIdx.x;
    const int lane = threadIdx.x;
    const int r    = lane >> 4;      // gate row
    const int o    = lane & 15;
    const bool act = (o < NW);
    const int oc   = act ? o : 0;

    __shared__ float zl[TSTEPS * NOUT];   // 10.24 KB

    // coalesced stage of this b's pre-activations
    {
        const float4* src4 = reinterpret_cast<const float4*>(zxT + (size_t)b * TSTEPS * NOUT);
        float4* dst4 = reinterpret_cast<float4*>(zl);
#pragma unroll
        for (int q = 0; q < 10; ++q) dst4[q * 64 + lane] = src4[q * 64 + lane];
    }

    float wh[NW];
#pragma unroll
    for (int j = 0; j < NW; ++j)
        wh[j] = W[(r * NW + oc) * FANIN + D_IN + j];

    __syncthreads();

    float hx_s[NW];
#pragma unroll
    for (int j = 0; j < NW; ++j) hx_s[j] = 0.f;

    float cx = 0.f, hv = 0.f;
    const int cidx = r * NW + oc;
    float zc = act ? zl[cidx] : 0.f;

    for (int t = 0; t < TSTEPS; ++t) {
        // prefetch next step's pre-activation (hides LDS latency)
        float zn = (act && t < TSTEPS - 1) ? zl[(t + 1) * NOUT + cidx] : 0.f;

        float z = zc;
#pragma unroll
        for (int j = 0; j < NW; ++j) z += hx_s[j] * wh[j];

        float cv = act ? __cosf(z) : 1.0f;

        // inclusive prefix product over the 16-lane group (DPP, VALU-only)
        float p = cv;
        p = dpp_shr_mul<0x111>(p);   // row_shr:1
        p = dpp_shr_mul<0x112>(p);   // row_shr:2
        p = dpp_shr_mul<0x114>(p);   // row_shr:4
        p = dpp_shr_mul<0x118>(p);   // row_shr:8

        // gate nonlinearity: sigmoid for f,i,o ; tanh for g (= 2*sigmoid(2x)-1)
        float a   = (r == 2) ? p + p : p;
        float sg  = __fdividef(1.f, 1.f + __expf(-a));
        float val = (r == 2) ? 2.f * sg - 1.f : sg;

        // gather i,g,o gate values onto row 0
        float v1 = __shfl(val, 16 + o);
        float v2 = __shfl(val, 32 + o);
        float v3 = __shfl(val, 48 + o);

        cx = val * cx + v1 * v2;               // row0: f*cx + i*g (others garbage, bounded)
        float e2 = __expf(cx + cx);
        float th = 1.f - __fdividef(2.f, e2 + 1.f);
        hv = v3 * th;

        if (r == 0 && act) out[((size_t)t * BATCH + b) * NW + o] = hv;

        // broadcast new hx via readlane -> SGPRs (off the LDS pipe)
#pragma unroll
        for (int j = 0; j < NW; ++j)
            hx_s[j] = __int_as_float(__builtin_amdgcn_readlane(__float_as_int(hv), j));

        zc = zn;
    }

    if (r == 0 && act) {
        hxout[b * NW + o] = hv;
        cxout[b * NW + o] = cx;
    }
}

extern "C" void kernel_launch(void* const* d_in, const int* in_sizes, int n_in,
                              void* d_out, int out_size, void* d_ws, size_t ws_size,
                              hipStream_t stream) {
    const float* x     = (const float*)d_in[0];  // (64,256,246)
    const float* W     = (const float*)d_in[1];  // (4,10,256)
    const float* bias  = (const float*)d_in[2];  // (4,10)
    const float* theta = (const float*)d_in[3];  // (4,10)

    float* out   = (float*)d_out;                        // (64,256,10)
    float* hxout = out + (size_t)TSTEPS * BATCH * NW;    // (256,10)
    float* cxout = hxout + (size_t)BATCH * NW;           // (256,10)

    float* Wp  = (float*)d_ws;                 // 15744 floats (61.5 KB)
    float* zxT = Wp + WP_ELEMS;                // (256,64,40) = 2.62 MB

    k_wt<<<(WP_ELEMS + 255) / 256, 256, 0, stream>>>(W, Wp);
    dim3 g1(TSTEPS, 4);
    k_zx<<<g1, 256, 0, stream>>>(x, Wp, bias, theta, zxT);
    k_scan<<<BATCH, 64, 0, stream>>>(zxT, W, out, hxout, cxout);
}

// Round 4
// 102.961 us; speedup vs baseline: 1.4584x; 1.2260x over previous
//
#include <hip/hip_runtime.h>
#include <hip/hip_bf16.h>

#define D_IN   246
#define NW     10
#define NG     4
#define NOUT   40
#define FANIN  256
#define BATCH  256
#define TSTEPS 64
#define WP_ELEMS (NG * D_IN * 16)   // 15744 floats, padded-o W

// ---------------- Kernel 0: transpose W -> Wp[g][i][16] (o padded to 16) ---------
__global__ __launch_bounds__(256) void k_wt(const float* __restrict__ W,
                                            float* __restrict__ Wp) {
    int e = blockIdx.x * 256 + threadIdx.x;
    if (e >= WP_ELEMS) return;
    int o = e & 15;
    int i = (e >> 4) % D_IN;
    int g = e / (16 * D_IN);
    float v = (o < NW) ? W[(g * NW + o) * FANIN + i] : 0.f;
    Wp[e] = v;
}

// ---------------- Kernel 1: zxT[b][t][g*10+o] = x.W + bias + theta ---------------
// grid (64 t, 4 bq), 512 threads = 8 waves: g = wave&3, kh = wave>>2 (K-split).
// K halves: kh0 -> i in [0,124), kh1 -> i in [124,246)  (both even lengths).
__global__ __launch_bounds__(512) void k_zx(
    const float* __restrict__ x,      // (64,256,246)
    const float* __restrict__ Wp,     // (4,246,16)
    const float* __restrict__ bias,   // (4,10)
    const float* __restrict__ theta,  // (4,10)
    float* __restrict__ zxT)          // (256,64,40)  b-major
{
    const int t    = blockIdx.x;
    const int bq   = blockIdx.y;
    const int tid  = threadIdx.x;
    const int lane = tid & 63;
    const int wv   = __builtin_amdgcn_readfirstlane(tid >> 6);
    const int g    = wv & 3;
    const int kh   = wv >> 2;

    __shared__ float xl[64 * D_IN];        // 62.98 KB, unpadded (stride 246: ~4-way, cheap)
    __shared__ float pr[NG][64][NW];       // 10.24 KB partials from kh=1

    // coalesced stage: 64 rows x 123 float2
    const float* xsrc = x + ((size_t)t * BATCH + bq * 64) * D_IN;
    for (int k = tid; k < 64 * 123; k += 512) {
        int row = k / 123;
        int j   = k - row * 123;
        float2 v = *reinterpret_cast<const float2*>(xsrc + row * D_IN + 2 * j);
        *reinterpret_cast<float2*>(xl + row * D_IN + 2 * j) = v;
    }
    __syncthreads();

    const int khbase = kh ? 124 : 0;
    const int npairs = kh ? 61 : 62;

    float acc[NW];
#pragma unroll
    for (int o = 0; o < NW; ++o) acc[o] = 0.f;

    const float* wg = Wp + (g * D_IN + khbase) * 16;   // wave-uniform -> s_load stream
    const float* xr = xl + lane * D_IN + khbase;

#pragma unroll 2
    for (int ii = 0; ii < npairs; ++ii) {
        float2 xv = *reinterpret_cast<const float2*>(xr + 2 * ii);
#pragma unroll
        for (int o = 0; o < NW; ++o) {
            acc[o] += xv.x * wg[(2 * ii)     * 16 + o];
            acc[o] += xv.y * wg[(2 * ii + 1) * 16 + o];
        }
    }

    if (kh == 1) {
#pragma unroll
        for (int o = 0; o < NW; ++o) pr[g][lane][o] = acc[o];
    }
    __syncthreads();

    if (kh == 0) {
#pragma unroll
        for (int o = 0; o < NW; ++o)
            acc[o] += pr[g][lane][o] + bias[g * NW + o] + theta[g * NW + o];
        const int b = bq * 64 + lane;
        float* zo = zxT + ((size_t)b * TSTEPS + t) * NOUT + g * NW;
#pragma unroll
        for (int q = 0; q < 5; ++q)
            *reinterpret_cast<float2*>(zo + 2 * q) = make_float2(acc[2 * q], acc[2 * q + 1]);
    }
}

// ---------------- Kernel 2: sequential LSTM scan, one wave per batch element ----
template <int CTRL>
__device__ __forceinline__ float dpp_shr_mul(float p) {
    int up = __builtin_amdgcn_update_dpp(__float_as_int(1.0f), __float_as_int(p),
                                         CTRL, 0xF, 0xF, false);
    return p * __int_as_float(up);
}

__global__ __launch_bounds__(64) void k_scan(
    const float* __restrict__ zxT,  // (256,64,40)
    const float* __restrict__ W,    // (4,10,256): recurrent cols 246..255
    float* __restrict__ out,        // (64,256,10)
    float* __restrict__ hxout,      // (256,10)
    float* __restrict__ cxout)      // (256,10)
{
    const int b    = blockIdx.x;
    const int lane = threadIdx.x;
    const int r    = lane >> 4;      // gate row
    const int o    = lane & 15;
    const bool act = (o < NW);
    const int oc   = act ? o : 0;

    __shared__ float zl[TSTEPS * NOUT];   // 10.24 KB

    {   // coalesced stage of this b's pre-activations
        const float4* src4 = reinterpret_cast<const float4*>(zxT + (size_t)b * TSTEPS * NOUT);
        float4* dst4 = reinterpret_cast<float4*>(zl);
#pragma unroll
        for (int q = 0; q < 10; ++q) dst4[q * 64 + lane] = src4[q * 64 + lane];
    }

    float wh[NW];
#pragma unroll
    for (int j = 0; j < NW; ++j)
        wh[j] = W[(r * NW + oc) * FANIN + D_IN + j];

    // per-lane activation constants: sigmoid for f,i,o; tanh(x)=2*sigmoid(2x)-1 for g
    const float am = (r == 2) ? 2.f : 1.f;
    const float vm = (r == 2) ? 2.f : 1.f;
    const float vc = (r == 2) ? -1.f : 0.f;
    // precomputed bpermute byte-indices for xor-gather across gate rows
    const int idx1 = (lane ^ 16) << 2;
    const int idx2 = (lane ^ 32) << 2;
    const int idx3 = (lane ^ 48) << 2;
    const bool q1 = (r & 1) != 0;
    const bool q2 = (r & 2) != 0;

    __syncthreads();

    float hx_s[NW];
#pragma unroll
    for (int j = 0; j < NW; ++j) hx_s[j] = 0.f;

    float cx = 0.f, hv = 0.f;
    const int cidx = r * NW + oc;
    float zc = act ? zl[cidx] : 0.f;

    for (int t = 0; t < TSTEPS; ++t) {
        // prefetch next step's pre-activation (off-chain)
        float zn = zl[(((t + 1) & 63) * NOUT) + cidx];

        // z = zc + hx.wh  (two parallel fma chains)
        float s0 = zc, s1 = 0.f;
#pragma unroll
        for (int j = 0; j < 5; ++j) {
            s0 = fmaf(hx_s[2 * j],     wh[2 * j],     s0);
            s1 = fmaf(hx_s[2 * j + 1], wh[2 * j + 1], s1);
        }
        float z = s0 + s1;

        float cv = __cosf(z);               // bounded for all lanes

        // inclusive prefix product over the 16-lane group (DPP, VALU-only)
        float p = cv;
        p = dpp_shr_mul<0x111>(p);
        p = dpp_shr_mul<0x112>(p);
        p = dpp_shr_mul<0x114>(p);
        p = dpp_shr_mul<0x118>(p);

        // activation with per-lane fused constants
        float e  = __expf(-(p * am));
        float sg = __fdividef(1.f, 1.f + e);
        float val = fmaf(sg, vm, vc);

        // gather the other 3 rows' values (parallel bpermutes, pre-indexed)
        int vi = __float_as_int(val);
        float a1 = __int_as_float(__builtin_amdgcn_ds_bpermute(idx1, vi)); // row^1
        float a2 = __int_as_float(__builtin_amdgcn_ds_bpermute(idx2, vi)); // row^2
        float a3 = __int_as_float(__builtin_amdgcn_ds_bpermute(idx3, vi)); // row^3

        float fv = q2 ? (q1 ? a3 : a2) : (q1 ? a1 : val);
        float iv = q2 ? (q1 ? a2 : a3) : (q1 ? val : a1);
        float gv = q2 ? (q1 ? a1 : val) : (q1 ? a3 : a2);
        float ov = q2 ? (q1 ? val : a1) : (q1 ? a2 : a3);

        cx = fmaf(fv, cx, iv * gv);          // all lanes redundantly
        float e2 = __expf(cx + cx);
        float th = 1.f - __fdividef(2.f, 1.f + e2);
        hv = ov * th;

        if (r == 0 && act) out[((size_t)t * BATCH + b) * NW + o] = hv;

        // broadcast hx via readlane -> SGPRs
#pragma unroll
        for (int j = 0; j < NW; ++j)
            hx_s[j] = __int_as_float(__builtin_amdgcn_readlane(__float_as_int(hv), j));

        zc = zn;
    }

    if (r == 0 && act) {
        hxout[b * NW + o] = hv;
        cxout[b * NW + o] = cx;
    }
}

extern "C" void kernel_launch(void* const* d_in, const int* in_sizes, int n_in,
                              void* d_out, int out_size, void* d_ws, size_t ws_size,
                              hipStream_t stream) {
    const float* x     = (const float*)d_in[0];  // (64,256,246)
    const float* W     = (const float*)d_in[1];  // (4,10,256)
    const float* bias  = (const float*)d_in[2];  // (4,10)
    const float* theta = (const float*)d_in[3];  // (4,10)

    float* out   = (float*)d_out;                        // (64,256,10)
    float* hxout = out + (size_t)TSTEPS * BATCH * NW;    // (256,10)
    float* cxout = hxout + (size_t)BATCH * NW;           // (256,10)

    float* Wp  = (float*)d_ws;                 // 15744 floats
    float* zxT = Wp + WP_ELEMS;                // (256,64,40) = 2.62 MB

    k_wt<<<(WP_ELEMS + 255) / 256, 256, 0, stream>>>(W, Wp);
    dim3 g1(TSTEPS, 4);
    k_zx<<<g1, 512, 0, stream>>>(x, Wp, bias, theta, zxT);
    k_scan<<<BATCH, 64, 0, stream>>>(zxT, W, out, hxout, cxout);
}